// Round 1
// baseline (1486.453 us; speedup 1.0000x reference)
//
#include <hip/hip_runtime.h>
#include <hip/hip_bf16.h>

#define EPSV 1e-5f

// z_g[h*E + e] = relu(b1[h] + sum_i ea[e*16+i] * w1[i*64+h])   (z stored transposed)
__global__ void k_edge_mlp(const float* __restrict__ ea, const float* __restrict__ w1,
                           const float* __restrict__ b1, float* __restrict__ zg, int E) {
    __shared__ float sEA[64][17];
    int t = threadIdx.x;
    int e0 = blockIdx.x * 64;
    for (int f = t; f < 64 * 16; f += 256) {
        int e = f >> 4, i = f & 15;
        int ge = e0 + e;
        sEA[e][i] = (ge < E) ? ea[(size_t)ge * 16 + i] : 0.f;
    }
    __syncthreads();
    int lane = t & 63, w = t >> 6;
    int ge = e0 + lane;
    #pragma unroll
    for (int hh = 0; hh < 16; ++hh) {
        int h = w * 16 + hh;
        float acc = b1[h];
        #pragma unroll
        for (int i = 0; i < 16; ++i) acc += sEA[lane][i] * w1[i * 64 + h];
        if (ge < E) zg[(size_t)h * E + ge] = fmaxf(acc, 0.f);
    }
}

// out[n*64+o] = bias[o] + sum_i hin[n*CIN+i] * root[i*64+o]
template <int CIN>
__global__ void k_root(const float* __restrict__ hin, const float* __restrict__ root,
                       const float* __restrict__ bias, float* __restrict__ out, int N) {
    int idx = blockIdx.x * blockDim.x + threadIdx.x;
    int n = idx >> 6, o = idx & 63;
    if (n >= N) return;
    float acc = bias[o];
    #pragma unroll
    for (int i = 0; i < CIN; ++i) acc += hin[(size_t)n * CIN + i] * root[i * 64 + o];
    out[(size_t)n * 64 + o] = acc;
}

// per 64-edge tile: acc[e,o] = sum_h z[e,h] * (X @ W2_h)[e,o] + (X @ B2)[e,o];  atomic scatter to agg[dst]
template <int CIN>
__global__ __launch_bounds__(256) void k_msg(const float* __restrict__ zg, const float* __restrict__ xin,
                                             const int* __restrict__ src, const int* __restrict__ dstv,
                                             const float* __restrict__ w2, const float* __restrict__ b2,
                                             float* __restrict__ agg, int E) {
    __shared__ float sXT[CIN][64];   // x transposed: [i][e]
    __shared__ float sZT[64][64];    // z transposed: [h][e]
    int t = threadIdx.x;
    int e0 = blockIdx.x * 64;

    #pragma unroll
    for (int r = 0; r < 16; ++r) {
        int f = r * 256 + t;
        int h = f >> 6, e = f & 63;
        int ge = e0 + e;
        sZT[h][e] = (ge < E) ? zg[(size_t)h * E + ge] : 0.f;  // zero kills invalid edges
    }
    for (int f = t; f < 64 * CIN; f += 256) {
        int e = f / CIN, i = f % CIN;
        int ge = e0 + e;
        int s = src[ge < E ? ge : (E - 1)];
        sXT[i][e] = xin[(size_t)s * CIN + i];
    }
    __syncthreads();

    int to = t & 15, te = t >> 4;  // o = to*4.., e = te*4..
    float acc[4][4] = {};
    for (int hs = 0; hs <= 64; ++hs) {
        const float* __restrict__ Brow = (hs < 64) ? (w2 + (size_t)hs * (CIN * 64)) : b2;
        float m[4][4] = {};
        #pragma unroll 8
        for (int i = 0; i < CIN; ++i) {
            float4 a = *(const float4*)&sXT[i][te * 4];
            float4 b = *(const float4*)&Brow[i * 64 + to * 4];
            m[0][0] += a.x * b.x; m[0][1] += a.x * b.y; m[0][2] += a.x * b.z; m[0][3] += a.x * b.w;
            m[1][0] += a.y * b.x; m[1][1] += a.y * b.y; m[1][2] += a.y * b.z; m[1][3] += a.y * b.w;
            m[2][0] += a.z * b.x; m[2][1] += a.z * b.y; m[2][2] += a.z * b.z; m[2][3] += a.z * b.w;
            m[3][0] += a.w * b.x; m[3][1] += a.w * b.y; m[3][2] += a.w * b.z; m[3][3] += a.w * b.w;
        }
        float zrA[4];
        if (hs < 64) {
            float4 zr = *(const float4*)&sZT[hs][te * 4];
            zrA[0] = zr.x; zrA[1] = zr.y; zrA[2] = zr.z; zrA[3] = zr.w;
        } else {
            zrA[0] = zrA[1] = zrA[2] = zrA[3] = 1.f;  // b2 step: theta += b2
        }
        #pragma unroll
        for (int ee = 0; ee < 4; ++ee) {
            #pragma unroll
            for (int oo = 0; oo < 4; ++oo) acc[ee][oo] += zrA[ee] * m[ee][oo];
        }
    }

    #pragma unroll
    for (int ee = 0; ee < 4; ++ee) {
        int ge = e0 + te * 4 + ee;
        if (ge < E) {
            int d = dstv[ge];
            float* ap = agg + (size_t)d * 64 + to * 4;
            atomicAdd(ap + 0, acc[ee][0]);
            atomicAdd(ap + 1, acc[ee][1]);
            atomicAdd(ap + 2, acc[ee][2]);
            atomicAdd(ap + 3, acc[ee][3]);
        }
    }
}

// in-place LayerNorm(feature dim, 64) + ReLU; one wave per node
__global__ void k_ln(float* __restrict__ h, const float* __restrict__ g, const float* __restrict__ b, int N) {
    int n = blockIdx.x * 4 + (threadIdx.x >> 6);
    int lane = threadIdx.x & 63;
    if (n >= N) return;
    float v = h[(size_t)n * 64 + lane];
    float s = v;
    #pragma unroll
    for (int d = 32; d > 0; d >>= 1) s += __shfl_xor(s, d, 64);
    float mean = s * (1.f / 64.f);
    float dv = v - mean;
    float s2 = dv * dv;
    #pragma unroll
    for (int d = 32; d > 0; d >>= 1) s2 += __shfl_xor(s2, d, 64);
    float var = s2 * (1.f / 64.f);
    float o = dv * rsqrtf(var + EPSV) * g[lane] + b[lane];
    h[(size_t)n * 64 + lane] = fmaxf(o, 0.f);
}

__global__ void k_pool(const float* __restrict__ h, const int* __restrict__ batch,
                       float* __restrict__ pool, float* __restrict__ cnt, int N) {
    int idx = blockIdx.x * blockDim.x + threadIdx.x;
    int n = idx >> 6, o = idx & 63;
    if (n >= N) return;
    int g = batch[n];
    atomicAdd(&pool[(size_t)g * 64 + o], h[(size_t)n * 64 + o]);
    if (o == 0) atomicAdd(&cnt[g], 1.f);
}

// per graph: hg = pool/cnt; out = relu(hg@fc1+b1)@fc2+b2   (block = 64 threads = 1 wave)
__global__ void k_head(const float* __restrict__ pool, const float* __restrict__ cnt,
                       const float* __restrict__ fc1w, const float* __restrict__ fc1b,
                       const float* __restrict__ fc2w, const float* __restrict__ fc2b,
                       float* __restrict__ out) {
    __shared__ float sh[64];
    __shared__ float sh2[32];
    int g = blockIdx.x;
    int t = threadIdx.x;
    float c = fmaxf(cnt[g], 1.f);
    sh[t] = pool[(size_t)g * 64 + t] / c;
    __syncthreads();
    if (t < 32) {
        float a = fc1b[t];
        #pragma unroll
        for (int o = 0; o < 64; ++o) a += sh[o] * fc1w[o * 32 + t];
        sh2[t] = fmaxf(a, 0.f);
    }
    __syncthreads();
    if (t == 0) {
        float a = fc2b[0];
        #pragma unroll
        for (int j = 0; j < 32; ++j) a += sh2[j] * fc2w[j];
        out[g] = a;
    }
}

extern "C" void kernel_launch(void* const* d_in, const int* in_sizes, int n_in,
                              void* d_out, int out_size, void* d_ws, size_t ws_size,
                              hipStream_t stream) {
    const float* x     = (const float*)d_in[0];
    const int*   ei    = (const int*)d_in[1];
    const float* ea    = (const float*)d_in[2];
    const int*   batch = (const int*)d_in[3];
    int E = in_sizes[1] / 2;
    int N = in_sizes[3];
    int G = out_size;  // DOUT = 1
    const int* src  = ei;
    const int* dstv = ei + E;

    const float* P[24];
    for (int i = 0; i < 24; ++i) P[i] = (const float*)d_in[4 + i];
    // per-layer base l*8: 0 w1, 1 b1, 2 w2, 3 b2, 4 root, 5 bias, 6 ln_g, 7 ln_b
    const float* fc1w = (const float*)d_in[28];
    const float* fc1b = (const float*)d_in[29];
    const float* fc2w = (const float*)d_in[30];
    const float* fc2b = (const float*)d_in[31];

    float* ws   = (float*)d_ws;
    float* zg   = ws;                        // 64*E
    float* hA   = zg + (size_t)64 * E;       // N*64
    float* hB   = hA + (size_t)N * 64;       // N*64
    float* pool = hB + (size_t)N * 64;       // G*64
    float* cnt  = pool + (size_t)G * 64;     // G

    hipMemsetAsync(pool, 0, (size_t)(G * 64 + G) * sizeof(float), stream);

    int ebl = (E + 63) / 64;
    int n64 = (N * 64 + 255) / 256;
    int nln = (N + 3) / 4;

    // ---- layer 1 (cin = 32) ----
    k_edge_mlp<<<ebl, 256, 0, stream>>>(ea, P[0], P[1], zg, E);
    k_root<32><<<n64, 256, 0, stream>>>(x, P[4], P[5], hA, N);
    k_msg<32><<<ebl, 256, 0, stream>>>(zg, x, src, dstv, P[2], P[3], hA, E);
    k_ln<<<nln, 256, 0, stream>>>(hA, P[6], P[7], N);

    // ---- layer 2 (cin = 64) ----
    k_edge_mlp<<<ebl, 256, 0, stream>>>(ea, P[8], P[9], zg, E);
    k_root<64><<<n64, 256, 0, stream>>>(hA, P[12], P[13], hB, N);
    k_msg<64><<<ebl, 256, 0, stream>>>(zg, hA, src, dstv, P[10], P[11], hB, E);
    k_ln<<<nln, 256, 0, stream>>>(hB, P[14], P[15], N);

    // ---- layer 3 (cin = 64) ----
    k_edge_mlp<<<ebl, 256, 0, stream>>>(ea, P[16], P[17], zg, E);
    k_root<64><<<n64, 256, 0, stream>>>(hB, P[20], P[21], hA, N);
    k_msg<64><<<ebl, 256, 0, stream>>>(zg, hB, src, dstv, P[18], P[19], hA, E);
    k_ln<<<nln, 256, 0, stream>>>(hA, P[22], P[23], N);

    // ---- pool + head ----
    k_pool<<<n64, 256, 0, stream>>>(hA, batch, pool, cnt, N);
    k_head<<<G, 64, 0, stream>>>(pool, cnt, fc1w, fc1b, fc2w, fc2b, (float*)d_out);
}

// Round 2
// 499.048 us; speedup vs baseline: 2.9786x; 2.9786x over previous
//
#include <hip/hip_runtime.h>
#include <hip/hip_bf16.h>

#define EPSV 1e-5f

typedef __attribute__((ext_vector_type(8))) short bf16x8;
typedef __attribute__((ext_vector_type(16))) float f32x16;

static __device__ __forceinline__ short f2bf(float f) {
    __hip_bfloat16 b = __float2bfloat16(f);
    return __builtin_bit_cast(short, b);
}
static __device__ __forceinline__ float bf2f(short s) {
    unsigned u = ((unsigned)(unsigned short)s) << 16;
    return __builtin_bit_cast(float, u);
}
static __device__ __forceinline__ unsigned pk2(float lo, float hi) {
    unsigned r;
    asm("v_cvt_pk_bf16_f32 %0, %1, %2" : "=v"(r) : "v"(lo), "v"(hi));
    return r;
}

// f32 -> bf16 bulk convert
__global__ void k_cvt(const float* __restrict__ x, short* __restrict__ xb, int n) {
    int i = blockIdx.x * blockDim.x + threadIdx.x;
    if (i < n) xb[i] = f2bf(x[i]);
}

// w2t[h][o][i] = bf16(w2[h][i*64+o]) for h<64 ; b2[i*64+o] for h==64
template <int CIN>
__global__ void k_prep_w2(const float* __restrict__ w2, const float* __restrict__ b2,
                          short* __restrict__ w2t) {
    int idx = blockIdx.x * blockDim.x + threadIdx.x;
    int total = 65 * 64 * CIN;
    if (idx >= total) return;
    int i = idx % CIN;
    int rest = idx / CIN;
    int o = rest & 63;
    int h = rest >> 6;
    float v = (h < 64) ? w2[(size_t)h * (CIN * 64) + i * 64 + o] : b2[i * 64 + o];
    w2t[idx] = f2bf(v);
}

// zgb[h*E + e] = bf16(relu(b1[h] + sum_i ea[e*16+i] * w1[i*64+h]))
__global__ void k_edge_mlp(const float* __restrict__ ea, const float* __restrict__ w1,
                           const float* __restrict__ b1, short* __restrict__ zgb, int E) {
    __shared__ float sEA[64][17];
    int t = threadIdx.x;
    int e0 = blockIdx.x * 64;
    for (int f = t; f < 64 * 16; f += 256) {
        int e = f >> 4, i = f & 15;
        int ge = e0 + e;
        sEA[e][i] = (ge < E) ? ea[(size_t)ge * 16 + i] : 0.f;
    }
    __syncthreads();
    int lane = t & 63, w = t >> 6;
    int ge = e0 + lane;
    #pragma unroll
    for (int hh = 0; hh < 16; ++hh) {
        int h = w * 16 + hh;
        float acc = b1[h];
        #pragma unroll
        for (int i = 0; i < 16; ++i) acc += sEA[lane][i] * w1[i * 64 + h];
        if (ge < E) zgb[(size_t)h * E + ge] = f2bf(fmaxf(acc, 0.f));
    }
}

// out[n*64+o] = bias[o] + sum_i hin[n*CIN+i] * root[i*64+o]   (also inits agg)
template <int CIN>
__global__ void k_root(const float* __restrict__ hin, const float* __restrict__ root,
                       const float* __restrict__ bias, float* __restrict__ out, int N) {
    int idx = blockIdx.x * blockDim.x + threadIdx.x;
    int n = idx >> 6, o = idx & 63;
    if (n >= N) return;
    float acc = bias[o];
    #pragma unroll
    for (int i = 0; i < CIN; ++i) acc += hin[(size_t)n * CIN + i] * root[i * 64 + o];
    out[(size_t)n * 64 + o] = acc;
}

// MFMA message kernel: per 64-edge tile, acc[e,o] = sum_{h<=64} z(e,h) * (x[src(e)] @ W2t[h])[o]
// A[32x16] = bf16(z*x) built in regs; B[16x32] = w2t from L2; atomic scatter to agg[dst].
template <int CIN>
__global__ __launch_bounds__(256) void k_msg(const short* __restrict__ zgb, const short* __restrict__ xb,
                                             const int* __restrict__ src, const int* __restrict__ dstv,
                                             const short* __restrict__ w2t,
                                             float* __restrict__ agg, int E) {
    constexpr int CH = CIN / 16;  // K-chunks of 16 per h
    __shared__ float sZT[64][64];
    int t = threadIdx.x;
    int e0 = blockIdx.x * 64;

    // stage z tile (f32 in LDS), zero for invalid edges
    for (int f = t; f < 64 * 64; f += 256) {
        int hh = f >> 6, e = f & 63;
        int ge = e0 + e;
        sZT[hh][e] = (ge < E) ? bf2f(zgb[(size_t)hh * E + ge]) : 0.f;
    }

    int lane = t & 63, w = t >> 6;
    int rowgrp = w >> 1;           // 0/1: which 32 edges
    int colgrp = w & 1;            // 0/1: which 32 output cols
    int kgrp = lane >> 5;          // 0/1: K sub-block
    int rowloc = rowgrp * 32 + (lane & 31);
    int erow = e0 + rowloc;
    int ncol = colgrp * 32 + (lane & 31);

    // load this lane's x slices (bf16), keep raw bf16 for the h==64 (b2, z=1) step
    int srow = src[min(erow, E - 1)];
    union XW { bf16x8 v; short s[8]; };
    XW xw[CH];
    float xv[CH * 8];
    #pragma unroll
    for (int c = 0; c < CH; ++c) {
        xw[c].v = *reinterpret_cast<const bf16x8*>(xb + (size_t)srow * CIN + c * 16 + kgrp * 8);
        #pragma unroll
        for (int j = 0; j < 8; ++j) xv[c * 8 + j] = bf2f(xw[c].s[j]);
    }

    __syncthreads();

    const short* bp = w2t + (size_t)ncol * CIN + kgrp * 8;

    f32x16 acc;
    #pragma unroll
    for (int r = 0; r < 16; ++r) acc[r] = 0.f;

    union AF { unsigned u[4]; bf16x8 v; };

    #pragma unroll 1
    for (int h = 0; h < 64; ++h) {
        const short* bph = bp + (size_t)h * (64 * CIN);
        bf16x8 bfr[CH];
        #pragma unroll
        for (int c = 0; c < CH; ++c) bfr[c] = *reinterpret_cast<const bf16x8*>(bph + c * 16);
        float zf = sZT[h][rowloc];
        #pragma unroll
        for (int c = 0; c < CH; ++c) {
            AF af;
            af.u[0] = pk2(zf * xv[c * 8 + 0], zf * xv[c * 8 + 1]);
            af.u[1] = pk2(zf * xv[c * 8 + 2], zf * xv[c * 8 + 3]);
            af.u[2] = pk2(zf * xv[c * 8 + 4], zf * xv[c * 8 + 5]);
            af.u[3] = pk2(zf * xv[c * 8 + 6], zf * xv[c * 8 + 7]);
            acc = __builtin_amdgcn_mfma_f32_32x32x16_bf16(af.v, bfr[c], acc, 0, 0, 0);
        }
    }
    // h == 64: the b2 term (z = 1, A = x directly, exact bf16 bits already loaded)
    {
        const short* bph = bp + (size_t)64 * (64 * CIN);
        #pragma unroll
        for (int c = 0; c < CH; ++c) {
            bf16x8 bv = *reinterpret_cast<const bf16x8*>(bph + c * 16);
            acc = __builtin_amdgcn_mfma_f32_32x32x16_bf16(xw[c].v, bv, acc, 0, 0, 0);
        }
    }

    // scatter: C/D layout col=lane&31, row=(r&3)+8*(r>>2)+4*(lane>>5)
    #pragma unroll
    for (int r = 0; r < 16; ++r) {
        int row = (r & 3) + 8 * (r >> 2) + 4 * kgrp;
        int ge = e0 + rowgrp * 32 + row;
        if (ge < E) {
            int d = dstv[ge];
            atomicAdd(&agg[(size_t)d * 64 + ncol], acc[r]);
        }
    }
}

// in-place LayerNorm + ReLU; also emits bf16 copy for next layer's MFMA input
__global__ void k_ln(float* __restrict__ h, const float* __restrict__ g, const float* __restrict__ b,
                     short* __restrict__ hb, int N) {
    int n = blockIdx.x * 4 + (threadIdx.x >> 6);
    int lane = threadIdx.x & 63;
    if (n >= N) return;
    float v = h[(size_t)n * 64 + lane];
    float s = v;
    #pragma unroll
    for (int d = 32; d > 0; d >>= 1) s += __shfl_xor(s, d, 64);
    float mean = s * (1.f / 64.f);
    float dv = v - mean;
    float s2 = dv * dv;
    #pragma unroll
    for (int d = 32; d > 0; d >>= 1) s2 += __shfl_xor(s2, d, 64);
    float var = s2 * (1.f / 64.f);
    float o = fmaxf(dv * rsqrtf(var + EPSV) * g[lane] + b[lane], 0.f);
    h[(size_t)n * 64 + lane] = o;
    hb[(size_t)n * 64 + lane] = f2bf(o);
}

// fused mean-pool (binary search on sorted batch, no atomics) + MLP head
__global__ void k_pool_head(const float* __restrict__ h, const int* __restrict__ batch,
                            const float* __restrict__ fc1w, const float* __restrict__ fc1b,
                            const float* __restrict__ fc2w, const float* __restrict__ fc2b,
                            float* __restrict__ out, int N) {
    __shared__ float sh[64];
    __shared__ float sh2[32];
    int g = blockIdx.x;
    int t = threadIdx.x;
    // lower_bound(batch, g) and lower_bound(batch, g+1)
    int lo = 0, hi = N;
    while (lo < hi) { int m = (lo + hi) >> 1; if (batch[m] < g) lo = m + 1; else hi = m; }
    int s0 = lo;
    lo = s0; hi = N;
    while (lo < hi) { int m = (lo + hi) >> 1; if (batch[m] < g + 1) lo = m + 1; else hi = m; }
    int s1 = lo;
    float s = 0.f;
    for (int n = s0; n < s1; ++n) s += h[(size_t)n * 64 + t];
    float c = fmaxf((float)(s1 - s0), 1.f);
    sh[t] = s / c;
    __syncthreads();
    if (t < 32) {
        float a = fc1b[t];
        #pragma unroll
        for (int o = 0; o < 64; ++o) a += sh[o] * fc1w[o * 32 + t];
        sh2[t] = fmaxf(a, 0.f);
    }
    __syncthreads();
    if (t == 0) {
        float a = fc2b[0];
        #pragma unroll
        for (int j = 0; j < 32; ++j) a += sh2[j] * fc2w[j];
        out[g] = a;
    }
}

extern "C" void kernel_launch(void* const* d_in, const int* in_sizes, int n_in,
                              void* d_out, int out_size, void* d_ws, size_t ws_size,
                              hipStream_t stream) {
    const float* x     = (const float*)d_in[0];
    const int*   ei    = (const int*)d_in[1];
    const float* ea    = (const float*)d_in[2];
    const int*   batch = (const int*)d_in[3];
    int E = in_sizes[1] / 2;
    int N = in_sizes[3];
    int G = out_size;  // DOUT = 1
    const int* src  = ei;
    const int* dstv = ei + E;

    const float* P[24];
    for (int i = 0; i < 24; ++i) P[i] = (const float*)d_in[4 + i];
    const float* fc1w = (const float*)d_in[28];
    const float* fc1b = (const float*)d_in[29];
    const float* fc2w = (const float*)d_in[30];
    const float* fc2b = (const float*)d_in[31];

    // workspace layout
    float* hA  = (float*)d_ws;                 // N*64 f32
    float* hB  = hA + (size_t)N * 64;          // N*64 f32
    short* zgb = (short*)(hB + (size_t)N * 64);// 64*E bf16
    short* xbA = zgb + (size_t)64 * E;         // N*64 bf16
    short* xbB = xbA + (size_t)N * 64;         // N*64 bf16
    short* w2t = xbB + (size_t)N * 64;         // 65*64*64 bf16 (reused per layer)

    int ebl = (E + 63) / 64;
    int n64 = (N * 64 + 255) / 256;
    int nln = (N + 3) / 4;
    int pw64 = (65 * 64 * 64 + 255) / 256;
    int pw32 = (65 * 64 * 32 + 255) / 256;

    // layer-1 input -> bf16
    k_cvt<<<(N * 32 + 255) / 256, 256, 0, stream>>>(x, xbA, N * 32);

    // ---- layer 1 (cin = 32) ----
    k_prep_w2<32><<<pw32, 256, 0, stream>>>(P[2], P[3], w2t);
    k_edge_mlp<<<ebl, 256, 0, stream>>>(ea, P[0], P[1], zgb, E);
    k_root<32><<<n64, 256, 0, stream>>>(x, P[4], P[5], hA, N);
    k_msg<32><<<ebl, 256, 0, stream>>>(zgb, xbA, src, dstv, w2t, hA, E);
    k_ln<<<nln, 256, 0, stream>>>(hA, P[6], P[7], xbB, N);

    // ---- layer 2 (cin = 64) ----
    k_prep_w2<64><<<pw64, 256, 0, stream>>>(P[10], P[11], w2t);
    k_edge_mlp<<<ebl, 256, 0, stream>>>(ea, P[8], P[9], zgb, E);
    k_root<64><<<n64, 256, 0, stream>>>(hA, P[12], P[13], hB, N);
    k_msg<64><<<ebl, 256, 0, stream>>>(zgb, xbB, src, dstv, w2t, hB, E);
    k_ln<<<nln, 256, 0, stream>>>(hB, P[14], P[15], xbA, N);

    // ---- layer 3 (cin = 64) ----
    k_prep_w2<64><<<pw64, 256, 0, stream>>>(P[18], P[19], w2t);
    k_edge_mlp<<<ebl, 256, 0, stream>>>(ea, P[16], P[17], zgb, E);
    k_root<64><<<n64, 256, 0, stream>>>(hB, P[20], P[21], hA, N);
    k_msg<64><<<ebl, 256, 0, stream>>>(zgb, xbA, src, dstv, w2t, hA, E);
    k_ln<<<nln, 256, 0, stream>>>(hA, P[22], P[23], xbB, N);

    // ---- fused pool + head ----
    k_pool_head<<<G, 64, 0, stream>>>(hA, batch, fc1w, fc1b, fc2w, fc2b, (float*)d_out, N);
}